// Round 1
// baseline (164.417 us; speedup 1.0000x reference)
//
#include <hip/hip_runtime.h>
#include <stdint.h>

typedef _Float16 f16;
typedef _Float16 f16x8 __attribute__((ext_vector_type(8)));
typedef _Float16 f16x4 __attribute__((ext_vector_type(4)));
typedef float f32x4 __attribute__((ext_vector_type(4)));

#define D_DIM 4096
#define H_DIM 256
#define E_DIM 64
#define BM 32
#define BK 64

// ---------- transpose + f32->f16 convert: dst[n][k] = src[k][n] ----------
// tiles: 32 (k) x 64 (n); grid = (K/32)*(N/64)
__global__ void transpose_cvt_kernel(const float* __restrict__ src,
                                     f16* __restrict__ dst,
                                     int K, int N, int ntilesN) {
  __shared__ float tile[32][65];
  const int b = blockIdx.x;
  const int kb = b / ntilesN;
  const int nb = b % ntilesN;
  const int t = threadIdx.x;
#pragma unroll
  for (int i = 0; i < 2; ++i) {
    const int idx = t * 2 + i;        // 0..511 float4s
    const int k = idx >> 4;           // 0..31
    const int n4 = (idx & 15) << 2;   // 0..60
    const float4 v = *(const float4*)(src + (size_t)(kb * 32 + k) * N + nb * 64 + n4);
    tile[k][n4 + 0] = v.x; tile[k][n4 + 1] = v.y;
    tile[k][n4 + 2] = v.z; tile[k][n4 + 3] = v.w;
  }
  __syncthreads();
  const int n = t >> 2;               // 0..63
  const int k0 = (t & 3) << 3;        // 0,8,16,24
  f16x8 o;
#pragma unroll
  for (int j = 0; j < 8; ++j) o[j] = (f16)tile[k0 + j][n];
  *(f16x8*)(dst + (size_t)(nb * 64 + n) * K + kb * 32 + k0) = o;
}

// ---------- GEMM1: h = relu(x @ w1 + b1), fp16 MFMA ----------
// BM=32 rows, BN=256 (full width -> x read exactly once), BK=64, 512 thr (8 waves 2x4)
__launch_bounds__(512)
__global__ void gemm1_kernel(const float* __restrict__ x,
                             const f16* __restrict__ w1t,   // [256][4096] fp16
                             const float* __restrict__ b1,
                             f16* __restrict__ h) {          // [8192][256] fp16
  // elem (row,k) stored at row*BK + (k ^ ((row&7)<<3))  -- XOR swizzle, bank-conflict-free
  __shared__ __align__(16) f16 As[BM * BK];
  __shared__ __align__(16) f16 Bs[H_DIM * BK];
  const int t = threadIdx.x;
  const int lane = t & 63;
  const int w = t >> 6;
  const int wm = w >> 2;     // 0..1
  const int wn = w & 3;      // 0..3
  const int brow = blockIdx.x * BM;
  const int g = lane >> 4;   // 0..3 (k-group)
  const int r = lane & 15;

  f32x4 acc[4] = {{0.f,0.f,0.f,0.f},{0.f,0.f,0.f,0.f},{0.f,0.f,0.f,0.f},{0.f,0.f,0.f,0.f}};

  const int a_row = t >> 4;            // 0..31
  const int a_col = (t & 15) << 2;     // 0..60 (mult of 4)
  const int a_sw  = a_col ^ ((a_row & 7) << 3);

  for (int kt = 0; kt < D_DIM / BK; ++kt) {
    const int kg = kt * BK;
    // stage A: 32x64 f32 -> f16 swizzled
    {
      const float4 v = *(const float4*)(x + (size_t)(brow + a_row) * D_DIM + kg + a_col);
      f16x4 hv; hv[0] = (f16)v.x; hv[1] = (f16)v.y; hv[2] = (f16)v.z; hv[3] = (f16)v.w;
      *(f16x4*)(As + a_row * BK + a_sw) = hv;
    }
    // stage B: 256x64 fp16 from w1t (k-contiguous rows)
#pragma unroll
    for (int i = 0; i < 4; ++i) {
      const int o = (t + i * 512) << 3;    // elem offset, 8-aligned
      const int c = o >> 6;                // 0..255
      const int kl = o & 63;
      const f16x8 v = *(const f16x8*)(w1t + (size_t)c * D_DIM + kg + kl);
      *(f16x8*)(Bs + c * BK + (kl ^ ((c & 7) << 3))) = v;
    }
    __syncthreads();
#pragma unroll
    for (int kk = 0; kk < 2; ++kk) {
      const int kb = kk * 32 + g * 8;
      const int arow = wm * 16 + r;
      const f16x8 af = *(const f16x8*)(As + arow * BK + (kb ^ ((arow & 7) << 3)));
#pragma unroll
      for (int nf = 0; nf < 4; ++nf) {
        const int bcol = wn * 64 + nf * 16 + r;
        const f16x8 bf = *(const f16x8*)(Bs + bcol * BK + (kb ^ ((bcol & 7) << 3)));
        acc[nf] = __builtin_amdgcn_mfma_f32_16x16x32_f16(af, bf, acc[nf], 0, 0, 0);
      }
    }
    __syncthreads();
  }
  // epilogue: + b1, relu, store fp16
#pragma unroll
  for (int nf = 0; nf < 4; ++nf) {
    const int col = wn * 64 + nf * 16 + r;
    const float bias = b1[col];
#pragma unroll
    for (int j = 0; j < 4; ++j) {
      const int row = wm * 16 + g * 4 + j;
      float v = acc[nf][j] + bias;
      v = v > 0.f ? v : 0.f;
      h[(size_t)(brow + row) * H_DIM + col] = (f16)v;
    }
  }
}

// ---------- GEMM2 + sparsemax (exact replication of reference bisection) ----------
// 128 thr = 2 waves, 16 rows/wave, grid = 8192/32 = 256
__launch_bounds__(128)
__global__ void gemm2_sparsemax_kernel(const f16* __restrict__ h,     // [8192][256]
                                       const f16* __restrict__ w2t,   // [64][256]
                                       const float* __restrict__ b2,
                                       float* __restrict__ out) {     // [8192][64] f32
  const int t = threadIdx.x;
  const int lane = t & 63;
  const int w = t >> 6;             // 0..1
  const int g = lane >> 4;          // 0..3
  const int r = lane & 15;
  const int rowbase = blockIdx.x * 32 + w * 16;

  f32x4 acc[4] = {{0.f,0.f,0.f,0.f},{0.f,0.f,0.f,0.f},{0.f,0.f,0.f,0.f},{0.f,0.f,0.f,0.f}};
#pragma unroll
  for (int ks = 0; ks < 8; ++ks) {
    const int kb = ks * 32 + g * 8;
    const f16x8 af = *(const f16x8*)(h + (size_t)(rowbase + r) * H_DIM + kb);
#pragma unroll
    for (int nf = 0; nf < 4; ++nf) {
      const f16x8 bf = *(const f16x8*)(w2t + (size_t)(nf * 16 + r) * H_DIM + kb);
      acc[nf] = __builtin_amdgcn_mfma_f32_16x16x32_f16(af, bf, acc[nf], 0, 0, 0);
    }
  }
  // u[j][nf] = utilities[rowbase + g*4 + j][nf*16 + r]
  float u[4][4];
#pragma unroll
  for (int nf = 0; nf < 4; ++nf) {
    const float bias = b2[nf * 16 + r];
#pragma unroll
    for (int j = 0; j < 4; ++j) u[j][nf] = acc[nf][j] + bias;
  }
  // row min/max across the 16-lane group (4 rows in parallel via j)
  float lo[4], hi[4];
#pragma unroll
  for (int j = 0; j < 4; ++j) {
    float mx = fmaxf(fmaxf(u[j][0], u[j][1]), fmaxf(u[j][2], u[j][3]));
    float mn = fminf(fminf(u[j][0], u[j][1]), fminf(u[j][2], u[j][3]));
#pragma unroll
    for (int m = 1; m < 16; m <<= 1) {
      mx = fmaxf(mx, __shfl_xor(mx, m));
      mn = fminf(mn, __shfl_xor(mn, m));
    }
    lo[j] = mn - 10.0f;
    hi[j] = mx;
  }
  // 50 bisection iters, same arithmetic as reference
  for (int it = 0; it < 50; ++it) {
#pragma unroll
    for (int j = 0; j < 4; ++j) {
      const float mid = 0.5f * (lo[j] + hi[j]);
      float s = fmaxf(u[j][0] - mid, 0.f) + fmaxf(u[j][1] - mid, 0.f)
              + fmaxf(u[j][2] - mid, 0.f) + fmaxf(u[j][3] - mid, 0.f);
#pragma unroll
      for (int m = 1; m < 16; m <<= 1) s += __shfl_xor(s, m);
      const bool pos = (s - 1.0f) > 0.0f;
      lo[j] = pos ? mid : lo[j];
      hi[j] = pos ? hi[j] : mid;
    }
  }
#pragma unroll
  for (int j = 0; j < 4; ++j) {
    const float tau = 0.5f * (lo[j] + hi[j]);
    const float p0 = fmaxf(u[j][0] - tau, 0.f);
    const float p1 = fmaxf(u[j][1] - tau, 0.f);
    const float p2 = fmaxf(u[j][2] - tau, 0.f);
    const float p3 = fmaxf(u[j][3] - tau, 0.f);
    float s = p0 + p1 + p2 + p3;
#pragma unroll
    for (int m = 1; m < 16; m <<= 1) s += __shfl_xor(s, m);
    const float inv = 1.0f / (s + 1e-8f);
    const int row = rowbase + g * 4 + j;
    float* orow = out + (size_t)row * E_DIM + r;
    orow[0]  = p0 * inv;
    orow[16] = p1 * inv;
    orow[32] = p2 * inv;
    orow[48] = p3 * inv;
  }
}

extern "C" void kernel_launch(void* const* d_in, const int* in_sizes, int n_in,
                              void* d_out, int out_size, void* d_ws, size_t ws_size,
                              hipStream_t stream) {
  const float* x  = (const float*)d_in[0];
  const float* w1 = (const float*)d_in[1];
  const float* b1 = (const float*)d_in[2];
  const float* w2 = (const float*)d_in[3];
  const float* b2 = (const float*)d_in[4];
  float* out = (float*)d_out;

  char* wsb = (char*)d_ws;
  f16* w1t = (f16*)wsb;                              // [256][4096] = 2 MB
  f16* w2t = (f16*)(wsb + (2u << 20));               // [64][256]   = 32 KB
  f16* h   = (f16*)(wsb + (2u << 20) + (1u << 16));  // [8192][256] = 4 MB

  transpose_cvt_kernel<<<512, 256, 0, stream>>>(w1, w1t, D_DIM, H_DIM, H_DIM / 64);
  transpose_cvt_kernel<<<8,   256, 0, stream>>>(w2, w2t, H_DIM, E_DIM, E_DIM / 64);
  gemm1_kernel<<<8192 / BM, 512, 0, stream>>>(x, w1t, b1, h);
  gemm2_sparsemax_kernel<<<8192 / 32, 128, 0, stream>>>(h, w2t, b2, out);
}

// Round 2
// 55.029 us; speedup vs baseline: 2.9878x; 2.9878x over previous
//
#include <hip/hip_runtime.h>
#include <stdint.h>

typedef _Float16 f16;
typedef _Float16 f16x8 __attribute__((ext_vector_type(8)));
typedef _Float16 f16x4 __attribute__((ext_vector_type(4)));
typedef float f32x4 __attribute__((ext_vector_type(4)));

#define D_DIM 4096
#define H_DIM 256
#define E_DIM 64
#define BM 32
#define BK 64
#define NKT (D_DIM / BK)  // 64

// ---- pack w1 [4096][256] f32 -> w1s: MFMA B-fragment order, f16 ----
// f16 index: ((kt*16 + c16)*2 + kk)*512 + lane*8 + j
// value    : w1[(kt*64 + kk*32 + (lane>>4)*8 + j)][c16*16 + (lane&15)]
__global__ void pack_w1_kernel(const float* __restrict__ w1, f16* __restrict__ w1s) {
  const int u = blockIdx.x * blockDim.x + threadIdx.x;  // 0..131071
  const int lane = u & 63;
  const int kk = (u >> 6) & 1;
  const int c16 = (u >> 7) & 15;
  const int kt = u >> 11;
  const int g = lane >> 4, r = lane & 15;
  const int k0 = kt * 64 + kk * 32 + g * 8;
  const int col = c16 * 16 + r;
  f16x8 o;
#pragma unroll
  for (int j = 0; j < 8; ++j) o[j] = (f16)w1[(size_t)(k0 + j) * H_DIM + col];
  *(f16x8*)(w1s + (size_t)u * 8) = o;
}

// ---- pack w2 [256][64] f32 -> w2s fragment order ----
// f16 index: (cg*8 + ks)*512 + lane*8 + j ; value: w2[ks*32+(lane>>4)*8+j][cg*16+(lane&15)]
__global__ void pack_w2_kernel(const float* __restrict__ w2, f16* __restrict__ w2s) {
  const int u = blockIdx.x * blockDim.x + threadIdx.x;  // 0..2047
  const int lane = u & 63;
  const int ks = (u >> 6) & 7;
  const int cg = u >> 9;
  const int g = lane >> 4, r = lane & 15;
  const int k0 = ks * 32 + g * 8;
  const int col = cg * 16 + r;
  f16x8 o;
#pragma unroll
  for (int j = 0; j < 8; ++j) o[j] = (f16)w2[(size_t)(k0 + j) * E_DIM + col];
  *(f16x8*)(w2s + (size_t)u * 8) = o;
}

// ---- fused: h=relu(x@w1+b1); u=h@w2+b2; p=sparsemax(u) ----
// grid 256 (1/CU), 512 thr = 8 waves; wave wn owns 32 rows x cols [wn*32, wn*32+32)
__launch_bounds__(512)
__global__ void fused_kernel(const float* __restrict__ x,
                             const f16* __restrict__ w1s,
                             const float* __restrict__ b1,
                             const f16* __restrict__ w2s,
                             const float* __restrict__ b2,
                             float* __restrict__ out) {
  __shared__ __align__(16) char smem[24576];
  f16* As0 = (f16*)smem;                   // [32*64] f16, swizzled
  f16* As1 = (f16*)(smem + 4096);
  f16* h_lds = (f16*)smem;                 // epilogue overlay: [32][256] swizzled
  float* u_lds = (float*)(smem + 16384);   // [32][64]

  const int t = threadIdx.x;
  const int lane = t & 63;
  const int wn = t >> 6;          // 0..7
  const int g = lane >> 4, r = lane & 15;
  const int brow = blockIdx.x * BM;

  // A staging: one float4 of x per thread per K-step
  const int a_row = t >> 4;             // 0..31
  const int a_col = (t & 15) << 2;      // 0..60
  const int a_sw = a_col ^ ((a_row & 7) << 3);
  const float* xrow = x + (size_t)(brow + a_row) * D_DIM + a_col;

  // B fragments: 4 x dwordx4 per wave per K-step, straight from packed w1s (L2)
  const f16* bptr = w1s + (size_t)(wn * 2) * 1024 + lane * 8;

  f32x4 acc[2][2] = {{{0.f,0.f,0.f,0.f},{0.f,0.f,0.f,0.f}},
                     {{0.f,0.f,0.f,0.f},{0.f,0.f,0.f,0.f}}};
  f16x8 B0[4], B1[4];
  float4 xE, xO;

#define LDX(kt) (*(const float4*)(xrow + (kt) * 64))
#define LDB(kt, B)                                                  \
  {                                                                 \
    const f16* p_ = bptr + (size_t)(kt) * 16384;                    \
    B[0] = *(const f16x8*)(p_);          /* kk0 ch0 */              \
    B[1] = *(const f16x8*)(p_ + 512);    /* kk1 ch0 */              \
    B[2] = *(const f16x8*)(p_ + 1024);   /* kk0 ch1 */              \
    B[3] = *(const f16x8*)(p_ + 1536);   /* kk1 ch1 */              \
  }
#define STW(As, v)                                                  \
  {                                                                 \
    f16x4 hv_;                                                      \
    hv_[0] = (f16)(v).x; hv_[1] = (f16)(v).y;                       \
    hv_[2] = (f16)(v).z; hv_[3] = (f16)(v).w;                       \
    *(f16x4*)((As) + a_row * 64 + a_sw) = hv_;                      \
  }
#define COMP(As, B)                                                            \
  {                                                                            \
    _Pragma("unroll") for (int kk = 0; kk < 2; ++kk) {                         \
      const int kb_ = kk * 32 + g * 8;                                         \
      _Pragma("unroll") for (int rh = 0; rh < 2; ++rh) {                       \
        const int arow_ = rh * 16 + r;                                         \
        const f16x8 af_ =                                                      \
            *(const f16x8*)((As) + arow_ * 64 + (kb_ ^ ((arow_ & 7) << 3)));   \
        _Pragma("unroll") for (int ch = 0; ch < 2; ++ch) {                     \
          acc[rh][ch] = __builtin_amdgcn_mfma_f32_16x16x32_f16(                \
              af_, B[kk + ch * 2], acc[rh][ch], 0, 0, 0);                      \
        }                                                                      \
      }                                                                        \
    }                                                                          \
  }
#define BAR()                                          \
  asm volatile("s_waitcnt lgkmcnt(0)" ::: "memory");   \
  __builtin_amdgcn_s_barrier();

  // prologue: As0=A(0), xE=x(1), xO=x(2), B0=B(0), B1=B(1)
  {
    float4 t0 = LDX(0);
    LDB(0, B0);
    LDB(1, B1);
    xE = LDX(1);
    xO = LDX(2);
    STW(As0, t0);
    BAR();
  }

#pragma unroll 1
  for (int s = 0; s < NKT; s += 2) {
    // even step s: compute As0/B0
    STW(As1, xE);                               // A(s+1) -> LDS
    xE = LDX(s + 3 < NKT ? s + 3 : NKT - 1);    // prefetch x(s+3), dist 2
    COMP(As0, B0);
    LDB(s + 2 < NKT ? s + 2 : NKT - 1, B0);     // prefetch B(s+2), dist 2
    BAR();
    // odd step s+1: compute As1/B1
    STW(As0, xO);                               // A(s+2) -> LDS
    xO = LDX(s + 4 < NKT ? s + 4 : NKT - 1);
    COMP(As1, B1);
    LDB(s + 3 < NKT ? s + 3 : NKT - 1, B1);
    BAR();
  }

  // ---- epilogue 1: h = relu(acc + b1) -> LDS (f16, k-swizzled) ----
#pragma unroll
  for (int rh = 0; rh < 2; ++rh)
#pragma unroll
    for (int ch = 0; ch < 2; ++ch) {
      const int col = wn * 32 + ch * 16 + r;
      const float bias = b1[col];
#pragma unroll
      for (int j = 0; j < 4; ++j) {
        const int row = rh * 16 + g * 4 + j;
        float v = acc[rh][ch][j] + bias;
        v = fmaxf(v, 0.f);
        h_lds[row * 256 + (col ^ ((row & 7) << 3))] = (f16)v;
      }
    }
  __syncthreads();

  // ---- epilogue 2: u = h @ w2 + b2 (one 16x16 tile per wave) ----
  const int rh2 = wn & 1;   // row half
  const int cg = wn >> 1;   // E col group (16)
  f32x4 acc2 = {0.f, 0.f, 0.f, 0.f};
  const f16* w2p = w2s + (size_t)(cg * 8) * 512 + lane * 8;
#pragma unroll
  for (int ks = 0; ks < 8; ++ks) {
    const int arow = rh2 * 16 + r;
    const int kb = ks * 32 + g * 8;
    const f16x8 af = *(const f16x8*)(h_lds + arow * 256 + (kb ^ ((arow & 7) << 3)));
    const f16x8 bf = *(const f16x8*)(w2p + ks * 512);
    acc2 = __builtin_amdgcn_mfma_f32_16x16x32_f16(af, bf, acc2, 0, 0, 0);
  }
  {
    const int col = cg * 16 + r;
    const float bias = b2[col];
#pragma unroll
    for (int j = 0; j < 4; ++j) {
      const int row = rh2 * 16 + g * 4 + j;
      u_lds[row * 64 + col] = acc2[j] + bias;
    }
  }
  __syncthreads();

  // ---- epilogue 3: sparsemax via bisection; 16 lanes per row, 4 vals/lane ----
  const int srow = wn * 4 + (lane >> 4);     // this lane group's row (0..31)
  const int scol = (lane & 15) << 2;         // 4 columns per lane
  const float4 uv = *(const float4*)(u_lds + srow * 64 + scol);
  float u0 = uv.x, u1 = uv.y, u2 = uv.z, u3 = uv.w;

  float mx = fmaxf(fmaxf(u0, u1), fmaxf(u2, u3));
  float mn = fminf(fminf(u0, u1), fminf(u2, u3));
#pragma unroll
  for (int m = 1; m < 16; m <<= 1) {
    mx = fmaxf(mx, __shfl_xor(mx, m));
    mn = fminf(mn, __shfl_xor(mn, m));
  }
  float lo = mn - 10.0f, hi = mx;
#pragma unroll 1
  for (int it = 0; it < 32; ++it) {
    const float mid = 0.5f * (lo + hi);
    float s = fmaxf(u0 - mid, 0.f) + fmaxf(u1 - mid, 0.f) +
              fmaxf(u2 - mid, 0.f) + fmaxf(u3 - mid, 0.f);
#pragma unroll
    for (int m = 1; m < 16; m <<= 1) s += __shfl_xor(s, m);
    const bool pos = (s - 1.0f) > 0.0f;
    lo = pos ? mid : lo;
    hi = pos ? hi : mid;
  }
  const float tau = 0.5f * (lo + hi);
  const float p0 = fmaxf(u0 - tau, 0.f);
  const float p1 = fmaxf(u1 - tau, 0.f);
  const float p2 = fmaxf(u2 - tau, 0.f);
  const float p3 = fmaxf(u3 - tau, 0.f);
  float sum = p0 + p1 + p2 + p3;
#pragma unroll
  for (int m = 1; m < 16; m <<= 1) sum += __shfl_xor(sum, m);
  const float inv = 1.0f / (sum + 1e-8f);
  float4 pv;
  pv.x = p0 * inv; pv.y = p1 * inv; pv.z = p2 * inv; pv.w = p3 * inv;
  *(float4*)(out + (size_t)(brow + srow) * E_DIM + scol) = pv;
}

extern "C" void kernel_launch(void* const* d_in, const int* in_sizes, int n_in,
                              void* d_out, int out_size, void* d_ws, size_t ws_size,
                              hipStream_t stream) {
  const float* x  = (const float*)d_in[0];
  const float* w1 = (const float*)d_in[1];
  const float* b1 = (const float*)d_in[2];
  const float* w2 = (const float*)d_in[3];
  const float* b2 = (const float*)d_in[4];
  float* out = (float*)d_out;

  char* wsb = (char*)d_ws;
  f16* w1s = (f16*)wsb;                   // 2 MB
  f16* w2s = (f16*)(wsb + (2u << 20));    // 32 KB

  pack_w1_kernel<<<512, 256, 0, stream>>>(w1, w1s);
  pack_w2_kernel<<<8, 256, 0, stream>>>(w2, w2s);
  fused_kernel<<<8192 / BM, 512, 0, stream>>>(x, w1s, b1, w2s, b2, out);
}

// Round 3
// 54.444 us; speedup vs baseline: 3.0200x; 1.0107x over previous
//
#include <hip/hip_runtime.h>
#include <stdint.h>

typedef _Float16 f16;
typedef _Float16 f16x8 __attribute__((ext_vector_type(8)));
typedef _Float16 f16x4 __attribute__((ext_vector_type(4)));
typedef float f32x4 __attribute__((ext_vector_type(4)));

#define D_DIM 4096
#define H_DIM 256
#define E_DIM 64
#define BM 32
#define BK 64
#define NKT 64

// ---- merged pack: w1 [4096][256] -> w1s fragment order; w2 [256][64] -> w2s ----
// w1s f16 index: ((kt*16 + c16)*2 + kk)*512 + lane*8 + j
//   = w1[(kt*64 + kk*32 + (lane>>4)*8 + j)][c16*16 + (lane&15)]
// w2s f16 index: (cg*8 + ks)*512 + lane*8 + j = w2[ks*32+(lane>>4)*8+j][cg*16+(lane&15)]
__global__ void pack_kernel(const float* __restrict__ w1, f16* __restrict__ w1s,
                            const float* __restrict__ w2, f16* __restrict__ w2s) {
  const int b = blockIdx.x;
  const int t = threadIdx.x;
  if (b < 512) {
    const int u = b * 256 + t;          // 0..131071
    const int lane = u & 63;
    const int kk = (u >> 6) & 1;
    const int c16 = (u >> 7) & 15;
    const int kt = u >> 11;
    const int g = lane >> 4, r = lane & 15;
    const int k0 = kt * 64 + kk * 32 + g * 8;
    const int col = c16 * 16 + r;
    f16x8 o;
#pragma unroll
    for (int j = 0; j < 8; ++j) o[j] = (f16)w1[(size_t)(k0 + j) * H_DIM + col];
    *(f16x8*)(w1s + (size_t)u * 8) = o;
  } else {
    const int u = (b - 512) * 256 + t;  // 0..2047
    const int lane = u & 63;
    const int ks = (u >> 6) & 7;
    const int cg = u >> 9;
    const int g = lane >> 4, r = lane & 15;
    const int k0 = ks * 32 + g * 8;
    const int col = cg * 16 + r;
    f16x8 o;
#pragma unroll
    for (int j = 0; j < 8; ++j) o[j] = (f16)w2[(size_t)(k0 + j) * E_DIM + col];
    *(f16x8*)(w2s + (size_t)u * 8) = o;
  }
}

// ---- fused: h=relu(x@w1+b1); u=h@w2+b2; p=sparsemax(u) ----
// grid 256, 512 thr (8 waves); ring-4 A-LDS, barrier per phase (2 K-steps)
__launch_bounds__(512)
__global__ void fused_kernel(const float* __restrict__ x,
                             const f16* __restrict__ w1s,
                             const float* __restrict__ b1,
                             const f16* __restrict__ w2s,
                             const float* __restrict__ b2,
                             float* __restrict__ out) {
  __shared__ __align__(16) char smem[24576];
  f16* As = (f16*)smem;                    // ring of 4 x 2048 f16 (4 KB each)
  f16* h_lds = (f16*)smem;                 // epilogue overlay [32][256] swizzled
  float* u_lds = (float*)(smem + 16384);   // [32][64]

  const int t = threadIdx.x;
  const int lane = t & 63;
  const int wn = t >> 6;          // 0..7
  const int g = lane >> 4, r = lane & 15;
  const int brow = blockIdx.x * BM;

  const int a_row = t >> 4;             // 0..31
  const int a_col = (t & 15) << 2;      // 0..60
  const int a_sw = a_col ^ ((a_row & 7) << 3);
  const float* xrow = x + (size_t)(brow + a_row) * D_DIM + a_col;
  const f16* bptr = w1s + (size_t)(wn * 2) * 1024 + lane * 8;

  f32x4 acc[2][2] = {{{0.f,0.f,0.f,0.f},{0.f,0.f,0.f,0.f}},
                     {{0.f,0.f,0.f,0.f},{0.f,0.f,0.f,0.f}}};
  f16x8 BA[8], BB[8];     // per-phase B frags: [step01*4 + kk + ch*2]
  float4 xA[2], xB[2];    // per-phase staged x (2 steps)

#define LDX(kt) (*(const float4*)(xrow + (size_t)(kt) * 64))
#define LDB(kt, B)                                                  \
  {                                                                 \
    const f16* p_ = bptr + (size_t)(kt) * 16384;                    \
    (B)[0] = *(const f16x8*)(p_);                                   \
    (B)[1] = *(const f16x8*)(p_ + 512);                             \
    (B)[2] = *(const f16x8*)(p_ + 1024);                            \
    (B)[3] = *(const f16x8*)(p_ + 1536);                            \
  }
#define STW(dst, v)                                                 \
  {                                                                 \
    f16x4 hv_;                                                      \
    hv_[0] = (f16)(v).x; hv_[1] = (f16)(v).y;                       \
    hv_[2] = (f16)(v).z; hv_[3] = (f16)(v).w;                       \
    *(f16x4*)((dst) + a_row * 64 + a_sw) = hv_;                     \
  }
#define COMP(Ab, B)                                                            \
  {                                                                            \
    _Pragma("unroll") for (int kk = 0; kk < 2; ++kk) {                         \
      const int kb_ = kk * 32 + g * 8;                                         \
      _Pragma("unroll") for (int rh = 0; rh < 2; ++rh) {                       \
        const int arow_ = rh * 16 + r;                                         \
        const f16x8 af_ =                                                      \
            *(const f16x8*)((Ab) + arow_ * 64 + (kb_ ^ ((arow_ & 7) << 3)));   \
        _Pragma("unroll") for (int ch = 0; ch < 2; ++ch) {                     \
          acc[rh][ch] = __builtin_amdgcn_mfma_f32_16x16x32_f16(                \
              af_, (B)[kk + ch * 2], acc[rh][ch], 0, 0, 0);                    \
        }                                                                      \
      }                                                                        \
    }                                                                          \
  }
#define BAR()                                          \
  asm volatile("s_waitcnt lgkmcnt(0)" ::: "memory");   \
  __builtin_amdgcn_s_barrier();

  // Phase P (steps s0=2P, s0+1): STW steps s0+2,s0+3 (regs from phase P-2's LDX);
  // LDX steps s0+6,s0+7; LDB steps s0+2,s0+3 into alt buffer; COMP s0,s0+1; BAR.
#define PHASE(s0, Bc, Bn, xc)                                     \
  {                                                               \
    STW(As + (((s0) + 2) & 3) * 2048, (xc)[0]);                   \
    STW(As + (((s0) + 3) & 3) * 2048, (xc)[1]);                   \
    {                                                             \
      int sx0 = (s0) + 6; if (sx0 > 63) sx0 = 63;                 \
      int sx1 = (s0) + 7; if (sx1 > 63) sx1 = 63;                 \
      (xc)[0] = LDX(sx0); (xc)[1] = LDX(sx1);                     \
    }                                                             \
    {                                                             \
      int sb0 = (s0) + 2; if (sb0 > 63) sb0 = 63;                 \
      int sb1 = (s0) + 3; if (sb1 > 63) sb1 = 63;                 \
      LDB(sb0, Bn); LDB(sb1, (Bn) + 4);                           \
    }                                                             \
    COMP(As + ((s0) & 3) * 2048, Bc);                             \
    COMP(As + (((s0) + 1) & 3) * 2048, (Bc) + 4);                 \
    BAR();                                                        \
  }

  // prologue: stage steps 0,1; B(0,1); x regs for steps 2..5
  {
    float4 t0 = LDX(0);
    float4 t1 = LDX(1);
    LDB(0, BA); LDB(1, BA + 4);
    xA[0] = LDX(2); xA[1] = LDX(3);
    xB[0] = LDX(4); xB[1] = LDX(5);
    STW(As, t0);
    STW(As + 2048, t1);
    BAR();
  }

#pragma unroll 1
  for (int pp = 0; pp < 16; ++pp) {
    const int s0 = pp * 4;
    PHASE(s0, BA, BB, xA);
    PHASE(s0 + 2, BB, BA, xB);
  }

  // ---- epilogue 1: h = relu(acc + b1) -> LDS (f16, k-swizzled) ----
#pragma unroll
  for (int rh = 0; rh < 2; ++rh)
#pragma unroll
    for (int ch = 0; ch < 2; ++ch) {
      const int col = wn * 32 + ch * 16 + r;
      const float bias = b1[col];
#pragma unroll
      for (int j = 0; j < 4; ++j) {
        const int row = rh * 16 + g * 4 + j;
        float v = acc[rh][ch][j] + bias;
        v = fmaxf(v, 0.f);
        h_lds[row * 256 + (col ^ ((row & 7) << 3))] = (f16)v;
      }
    }
  __syncthreads();

  // ---- epilogue 2: u = h @ w2 + b2 (one 16x16 tile per wave) ----
  const int rh2 = wn & 1;
  const int cg = wn >> 1;
  f32x4 acc2 = {0.f, 0.f, 0.f, 0.f};
  const f16* w2p = w2s + (size_t)(cg * 8) * 512 + lane * 8;
#pragma unroll
  for (int ks = 0; ks < 8; ++ks) {
    const int arow = rh2 * 16 + r;
    const int kb = ks * 32 + g * 8;
    const f16x8 af = *(const f16x8*)(h_lds + arow * 256 + (kb ^ ((arow & 7) << 3)));
    const f16x8 bf = *(const f16x8*)(w2p + ks * 512);
    acc2 = __builtin_amdgcn_mfma_f32_16x16x32_f16(af, bf, acc2, 0, 0, 0);
  }
  {
    const int col = cg * 16 + r;
    const float bias = b2[col];
#pragma unroll
    for (int j = 0; j < 4; ++j) {
      const int row = rh2 * 16 + g * 4 + j;
      u_lds[row * 64 + col] = acc2[j] + bias;
    }
  }
  __syncthreads();

  // ---- epilogue 3: bisection sparsemax; 16 lanes/row, 4 vals/lane ----
  const int srow = wn * 4 + (lane >> 4);
  const int scol = (lane & 15) << 2;
  const float4 uv = *(const float4*)(u_lds + srow * 64 + scol);
  float u0 = uv.x, u1 = uv.y, u2 = uv.z, u3 = uv.w;

  float mx = fmaxf(fmaxf(u0, u1), fmaxf(u2, u3));
  float mn = fminf(fminf(u0, u1), fminf(u2, u3));
#pragma unroll
  for (int m = 1; m < 16; m <<= 1) {
    mx = fmaxf(mx, __shfl_xor(mx, m));
    mn = fminf(mn, __shfl_xor(mn, m));
  }
  float lo = mn - 10.0f, hi = mx;
#pragma unroll 1
  for (int it = 0; it < 32; ++it) {
    const float mid = 0.5f * (lo + hi);
    float s = fmaxf(u0 - mid, 0.f) + fmaxf(u1 - mid, 0.f) +
              fmaxf(u2 - mid, 0.f) + fmaxf(u3 - mid, 0.f);
#pragma unroll
    for (int m = 1; m < 16; m <<= 1) s += __shfl_xor(s, m);
    const bool pos = (s - 1.0f) > 0.0f;
    lo = pos ? mid : lo;
    hi = pos ? hi : mid;
  }
  const float tau = 0.5f * (lo + hi);
  const float p0 = fmaxf(u0 - tau, 0.f);
  const float p1 = fmaxf(u1 - tau, 0.f);
  const float p2 = fmaxf(u2 - tau, 0.f);
  const float p3 = fmaxf(u3 - tau, 0.f);
  float sum = p0 + p1 + p2 + p3;
#pragma unroll
  for (int m = 1; m < 16; m <<= 1) sum += __shfl_xor(sum, m);
  const float inv = 1.0f / (sum + 1e-8f);
  float4 pv;
  pv.x = p0 * inv; pv.y = p1 * inv; pv.z = p2 * inv; pv.w = p3 * inv;
  *(float4*)(out + (size_t)(brow + srow) * E_DIM + scol) = pv;
}

extern "C" void kernel_launch(void* const* d_in, const int* in_sizes, int n_in,
                              void* d_out, int out_size, void* d_ws, size_t ws_size,
                              hipStream_t stream) {
  const float* x  = (const float*)d_in[0];
  const float* w1 = (const float*)d_in[1];
  const float* b1 = (const float*)d_in[2];
  const float* w2 = (const float*)d_in[3];
  const float* b2 = (const float*)d_in[4];
  float* out = (float*)d_out;

  char* wsb = (char*)d_ws;
  f16* w1s = (f16*)wsb;                   // 2 MB
  f16* w2s = (f16*)(wsb + (2u << 20));    // 32 KB

  pack_kernel<<<520, 256, 0, stream>>>(w1, w1s, w2, w2s);
  fused_kernel<<<8192 / BM, 512, 0, stream>>>(x, w1s, b1, w2s, b2, out);
}